// Round 1
// baseline (340.246 us; speedup 1.0000x reference)
//
#include <hip/hip_runtime.h>

#define LATENT 96
#define NCH    192
#define O3     288
#define NSEQ   4096
#define NB     8

typedef short bf16_t;  // bf16 storage as raw bits
typedef __attribute__((ext_vector_type(8))) short  short8;
typedef __attribute__((ext_vector_type(4))) short  short4_t;
typedef __attribute__((ext_vector_type(4))) float  f32x4;

__device__ __forceinline__ short f2bf(float f) {
  union { float f; unsigned u; } v; v.f = f;
  unsigned r = v.u + 0x7FFFu + ((v.u >> 16) & 1u);  // RNE, finite inputs
  return (short)(r >> 16);
}

__device__ __forceinline__ f32x4 mfma16(short8 a, short8 b, f32x4 c) {
  return __builtin_amdgcn_mfma_f32_16x16x32_bf16(a, b, c, 0, 0, 0);
}

// ---------------------------------------------------------------------------
// K1: t = Wt @ x + bt  (per batch, 288x192 @ 192x4096)
// MFMA orientation: D[m = n][col = o]  (A = x^T tile, B = Wt rows as-is)
// Outputs: tT[b][n][288] bf16 (for Q/K staging in K2), tV[b][96][n] bf16 (V).
// ---------------------------------------------------------------------------
__global__ __launch_bounds__(256) void k1_qkv(const float* __restrict__ x,
                                              const float* __restrict__ Wt,
                                              const float* __restrict__ bt,
                                              bf16_t* __restrict__ tT,
                                              bf16_t* __restrict__ tV) {
  const int tid = threadIdx.x;
  const int li = tid & 15, lg = (tid >> 4) & 3, wid = tid >> 6;
  const int b = blockIdx.z, m0 = blockIdx.y * 64, n0 = blockIdx.x * 64;

  __shared__ bf16_t Ws[64][200];  // Wt tile [o][c], rows 400B (25*16B)
  __shared__ bf16_t Xs[64][200];  // x^T tile [n][c]

  // stage Wt tile (rows o = m0..m0+63, zero-pad past 288)
  for (int e = tid; e < 64 * 192; e += 256) {
    int r = e / 192, c = e - r * 192;
    int o = m0 + r;
    float v = (o < O3) ? Wt[o * NCH + c] : 0.f;
    Ws[r][c] = f2bf(v);
  }
  // stage x tile transposed: Xs[n][c] = x[b][c][n0+n]
  const float* xb = x + (size_t)b * NCH * NSEQ + n0;
  for (int e = tid; e < 192 * 64; e += 256) {
    int n = e & 63, c = e >> 6;
    Xs[n][c] = f2bf(xb[(size_t)c * NSEQ + n]);
  }
  __syncthreads();

  f32x4 acc[4];
  #pragma unroll
  for (int s = 0; s < 4; ++s) { acc[s][0]=0.f; acc[s][1]=0.f; acc[s][2]=0.f; acc[s][3]=0.f; }

  #pragma unroll
  for (int kk = 0; kk < 6; ++kk) {
    short8 ax = *(const short8*)&Xs[16 * wid + li][32 * kk + 8 * lg];
    #pragma unroll
    for (int sub = 0; sub < 4; ++sub) {
      short8 bw = *(const short8*)&Ws[16 * sub + li][32 * kk + 8 * lg];
      acc[sub] = mfma16(ax, bw, acc[sub]);
    }
  }

  // epilogue: D row = n-within-wave (4*lg + r), col = o-within-sub (li)
  bf16_t* tTb = tT + (size_t)b * NSEQ * O3;
  bf16_t* tVb = tV + (size_t)b * LATENT * NSEQ;
  const int nbase = n0 + 16 * wid + 4 * lg;
  #pragma unroll
  for (int sub = 0; sub < 4; ++sub) {
    int o = m0 + 16 * sub + li;
    if (o < O3) {
      float bo = bt[o];
      #pragma unroll
      for (int r = 0; r < 4; ++r) {
        int nn = nbase + r;
        float v = acc[sub][r] + bo;
        bf16_t bv = f2bf(v);
        tTb[(size_t)nn * O3 + o] = bv;
        if (o >= LATENT && o < 2 * LATENT)
          tVb[(size_t)(o - LATENT) * NSEQ + nn] = bv;
      }
    }
  }
}

// ---------------------------------------------------------------------------
// K2: flash attention over q axis.  i = output position (softmax per i over q).
// Block: 4 waves, 64 i's (16 per wave). Loop q in tiles of 64.
// S-MFMA: D[m=q][n=i] = Qa^T x Ka   (A from Qs_T, B from Ks_T, k = c, 3 steps)
// PV-MFMA: D[m=c][n=i] += V x P     (A from Vs rows, B = P direct from regs)
// ---------------------------------------------------------------------------
__global__ __launch_bounds__(256) void k2_attn(const bf16_t* __restrict__ tT,
                                               const bf16_t* __restrict__ tV,
                                               bf16_t* __restrict__ ao) {
  const int tid = threadIdx.x;
  const int li = tid & 15, lg = (tid >> 4) & 3, wid = tid >> 6;
  const int b = blockIdx.y;
  const int i0 = blockIdx.x * 64;

  __shared__ bf16_t Ks[64][104];  // [i][c]  rows 208B (13*16B)
  __shared__ bf16_t Qs[64][104];  // [q][c]
  __shared__ bf16_t Vs[96][40];   // [c][q]  rows 80B (5*16B)

  const bf16_t* tTb = tT + (size_t)b * NSEQ * O3;
  const bf16_t* tVb = tV + (size_t)b * LATENT * NSEQ;

  // stage K tile once: Ks[i][c] = t[b][192+c][i0+i]  (tT rows are [n][o])
  for (int ch = tid; ch < 64 * 12; ch += 256) {
    int r = ch / 12, cc = ch % 12;
    *(short8*)&Ks[r][cc * 8] =
        *(const short8*)(tTb + (size_t)(i0 + r) * O3 + 2 * LATENT + cc * 8);
  }

  f32x4 Oa[6];
  #pragma unroll
  for (int s = 0; s < 6; ++s) { Oa[s][0]=0.f; Oa[s][1]=0.f; Oa[s][2]=0.f; Oa[s][3]=0.f; }
  float m_run = -3.0e38f, l_run = 0.f;
  const float inv_rdk = 0.10206207261596575f;  // 1/sqrt(96)

  for (int q0 = 0; q0 < NSEQ; q0 += 64) {
    __syncthreads();  // previous iteration readers done before overwrite
    for (int ch = tid; ch < 64 * 12; ch += 256) {
      int r = ch / 12, cc = ch % 12;
      *(short8*)&Qs[r][cc * 8] =
          *(const short8*)(tTb + (size_t)(q0 + r) * O3 + cc * 8);
    }
    for (int ch = tid; ch < 96 * 8; ch += 256) {
      int c = ch >> 3, cc = ch & 7;
      *(short8*)&Vs[c][cc * 8] =
          *(const short8*)(tVb + (size_t)c * NSEQ + q0 + cc * 8);
    }
    __syncthreads();

    // S'[q][i] for 64 q x this wave's 16 i
    f32x4 S[4];
    #pragma unroll
    for (int s = 0; s < 4; ++s) { S[s][0]=0.f; S[s][1]=0.f; S[s][2]=0.f; S[s][3]=0.f; }
    #pragma unroll
    for (int kk = 0; kk < 3; ++kk) {
      short8 bk = *(const short8*)&Ks[16 * wid + li][32 * kk + 8 * lg];
      #pragma unroll
      for (int s = 0; s < 4; ++s) {
        short8 aq = *(const short8*)&Qs[16 * s + li][32 * kk + 8 * lg];
        S[s] = mfma16(aq, bk, S[s]);
      }
    }

    // online softmax: lane holds 16 q-values (q = 16s + 4lg + r) for one i
    float p[16];
    float tmax = -3.0e38f;
    #pragma unroll
    for (int s = 0; s < 4; ++s)
      #pragma unroll
      for (int r = 0; r < 4; ++r) {
        float v = S[s][r] * inv_rdk;
        p[4 * s + r] = v;
        tmax = fmaxf(tmax, v);
      }
    tmax = fmaxf(tmax, __shfl_xor(tmax, 16));
    tmax = fmaxf(tmax, __shfl_xor(tmax, 32));
    float mnew = fmaxf(m_run, tmax);
    float scl = __expf(m_run - mnew);
    float lsum = 0.f;
    #pragma unroll
    for (int k = 0; k < 16; ++k) {
      p[k] = __expf(p[k] - mnew);
      lsum += p[k];
    }
    lsum += __shfl_xor(lsum, 16);
    lsum += __shfl_xor(lsum, 32);
    l_run = l_run * scl + lsum;
    m_run = mnew;
    #pragma unroll
    for (int t = 0; t < 6; ++t) {
      Oa[t][0] *= scl; Oa[t][1] *= scl; Oa[t][2] *= scl; Oa[t][3] *= scl;
    }

    // PV: k-map f(lg,j) = 16*ks*2? -> q = 32*ks + 16*(j>=4) + 4*lg + (j&3)
    // matches bp[j] = p[8*ks + j]  (p[4s+r] <-> q = 16s + 4lg + r)
    #pragma unroll
    for (int ks = 0; ks < 2; ++ks) {
      short8 bp;
      #pragma unroll
      for (int j = 0; j < 8; ++j) bp[j] = f2bf(p[8 * ks + j]);
      #pragma unroll
      for (int sub = 0; sub < 6; ++sub) {
        const bf16_t* vrow = &Vs[16 * sub + li][32 * ks + 4 * lg];
        short4_t lo = *(const short4_t*)(vrow);
        short4_t hi = *(const short4_t*)(vrow + 16);
        short8 av;
        #pragma unroll
        for (int j = 0; j < 4; ++j) { av[j] = lo[j]; av[4 + j] = hi[j]; }
        Oa[sub] = mfma16(av, bp, Oa[sub]);
      }
    }
  }

  // epilogue: ao[b][c][i] = Oa / l   (c = 16*sub + 4*lg + r, i = i0+16*wid+li)
  float linv = 1.f / l_run;
  bf16_t* aob = ao + (size_t)b * LATENT * NSEQ + i0 + 16 * wid + li;
  #pragma unroll
  for (int sub = 0; sub < 6; ++sub)
    #pragma unroll
    for (int r = 0; r < 4; ++r) {
      int c = 16 * sub + 4 * lg + r;
      aob[(size_t)c * NSEQ] = f2bf(Oa[sub][r] * linv);
    }
}

// ---------------------------------------------------------------------------
// K3: out = Wd @ ao + bd + x   (192x96 @ 96x4096 per batch, f32 out)
// MFMA orientation: D[m = o][col = n]  (A = Wd rows, B = ao^T tile)
// ---------------------------------------------------------------------------
__global__ __launch_bounds__(256) void k3_proj(const bf16_t* __restrict__ ao,
                                               const float* __restrict__ Wd,
                                               const float* __restrict__ bd,
                                               const float* __restrict__ x,
                                               float* __restrict__ out) {
  const int tid = threadIdx.x;
  const int li = tid & 15, lg = (tid >> 4) & 3, wid = tid >> 6;
  const int b = blockIdx.z, m0 = blockIdx.y * 64, n0 = blockIdx.x * 64;

  __shared__ bf16_t Ws[64][104];  // Wd tile [o][c]
  __shared__ bf16_t As[64][104];  // ao^T tile [n][c]

  for (int e = tid; e < 64 * 96; e += 256) {
    int r = e / 96, c = e - r * 96;
    Ws[r][c] = f2bf(Wd[(m0 + r) * LATENT + c]);
  }
  const bf16_t* aob = ao + (size_t)b * LATENT * NSEQ + n0;
  for (int e = tid; e < 96 * 64; e += 256) {
    int n = e & 63, c = e >> 6;
    As[n][c] = aob[(size_t)c * NSEQ + n];
  }
  __syncthreads();

  f32x4 acc[4];
  #pragma unroll
  for (int s = 0; s < 4; ++s) { acc[s][0]=0.f; acc[s][1]=0.f; acc[s][2]=0.f; acc[s][3]=0.f; }

  #pragma unroll
  for (int kk = 0; kk < 3; ++kk) {
    short8 aw = *(const short8*)&Ws[16 * wid + li][32 * kk + 8 * lg];
    #pragma unroll
    for (int sub = 0; sub < 4; ++sub) {
      short8 ba = *(const short8*)&As[16 * sub + li][32 * kk + 8 * lg];
      acc[sub] = mfma16(aw, ba, acc[sub]);
    }
  }

  // D row = o-within-wave (4lg + r), col = n-within-sub (li)
  const float* xb = x + ((size_t)b * NCH + m0) * NSEQ;
  float* ob = out + ((size_t)b * NCH + m0) * NSEQ;
  #pragma unroll
  for (int r = 0; r < 4; ++r) {
    int o = 16 * wid + 4 * lg + r;
    float bo = bd[m0 + o];
    #pragma unroll
    for (int sub = 0; sub < 4; ++sub) {
      int nn = n0 + 16 * sub + li;
      ob[(size_t)o * NSEQ + nn] = acc[sub][r] + bo + xb[(size_t)o * NSEQ + nn];
    }
  }
}

// ---------------------------------------------------------------------------
extern "C" void kernel_launch(void* const* d_in, const int* in_sizes, int n_in,
                              void* d_out, int out_size, void* d_ws, size_t ws_size,
                              hipStream_t stream) {
  const float* x  = (const float*)d_in[0];
  const float* Wt = (const float*)d_in[1];
  const float* bt = (const float*)d_in[2];
  const float* Wd = (const float*)d_in[3];
  const float* bd = (const float*)d_in[4];
  float* out = (float*)d_out;

  char* ws = (char*)d_ws;
  const size_t tT_bytes = (size_t)NB * NSEQ * O3 * 2;       // 18,874,368
  const size_t tV_bytes = (size_t)NB * LATENT * NSEQ * 2;   //  6,291,456
  bf16_t* tT = (bf16_t*)ws;
  bf16_t* tV = (bf16_t*)(ws + tT_bytes);
  bf16_t* ao = (bf16_t*)(ws + tT_bytes + tV_bytes);

  dim3 blk(256);
  k1_qkv<<<dim3(64, 5, NB), blk, 0, stream>>>(x, Wt, bt, tT, tV);
  k2_attn<<<dim3(64, NB), blk, 0, stream>>>(tT, tV, ao);
  k3_proj<<<dim3(64, 3, NB), blk, 0, stream>>>(ao, Wd, bd, x, out);
}

// Round 3
// 267.621 us; speedup vs baseline: 1.2714x; 1.2714x over previous
//
#include <hip/hip_runtime.h>

#define LATENT 96
#define NCH    192
#define O3     288
#define NSEQ   4096
#define NB     8

typedef short bf16_t;  // bf16 storage as raw bits
typedef __attribute__((ext_vector_type(8))) short  short8;
typedef __attribute__((ext_vector_type(4))) short  short4_t;
typedef __attribute__((ext_vector_type(4))) float  f32x4;

__device__ __forceinline__ short f2bf(float f) {
  union { float f; unsigned u; } v; v.f = f;
  unsigned r = v.u + 0x7FFFu + ((v.u >> 16) & 1u);  // RNE, finite inputs
  return (short)(r >> 16);
}

__device__ __forceinline__ f32x4 mfma16(short8 a, short8 b, f32x4 c) {
  return __builtin_amdgcn_mfma_f32_16x16x32_bf16(a, b, c, 0, 0, 0);
}

// ---------------------------------------------------------------------------
// K1: t = Wt @ x + bt  (per batch, 288x192 @ 192x4096)
// One block per (b, n-tile of 64); x staged ONCE; loop 5 m-tiles of 64.
// LDS-bounce epilogue -> coalesced 128B row writes of tT[n][288] and tV[c][n].
// ---------------------------------------------------------------------------
__global__ __launch_bounds__(256) void k1_qkv(const float* __restrict__ x,
                                              const float* __restrict__ Wt,
                                              const float* __restrict__ bt,
                                              bf16_t* __restrict__ tT,
                                              bf16_t* __restrict__ tV) {
  const int tid = threadIdx.x;
  const int li = tid & 15, lg = (tid >> 4) & 3, wid = tid >> 6;
  const int b = blockIdx.y, n0 = blockIdx.x * 64;

  // explicit single LDS block: Xs [64][200], Ws [64][200]; Tts/Tvs alias Ws
  __shared__ __align__(16) char sm1[51200];
  bf16_t* Xs = (bf16_t*)sm1;              // [64][200] x^T tile [n][c]
  bf16_t* Ws = (bf16_t*)(sm1 + 25600);    // [64][200] Wt tile [o][c]
  bf16_t* Tts = Ws;                        // [64][72]  bounce [n][o]
  bf16_t* Tvs = Ws + 64 * 72;              // [64][72]  bounce [o][n]

  // stage x tile transposed (float4 loads, coalesced)
  const float* xb = x + (size_t)b * NCH * NSEQ + n0;
  for (int e = tid; e < NCH * 16; e += 256) {
    int c = e >> 4, nq = e & 15;
    float4 xv = *(const float4*)(xb + (size_t)c * NSEQ + nq * 4);
    Xs[(4 * nq + 0) * 200 + c] = f2bf(xv.x);
    Xs[(4 * nq + 1) * 200 + c] = f2bf(xv.y);
    Xs[(4 * nq + 2) * 200 + c] = f2bf(xv.z);
    Xs[(4 * nq + 3) * 200 + c] = f2bf(xv.w);
  }

  bf16_t* tTb = tT + (size_t)b * NSEQ * O3;
  bf16_t* tVb = tV + (size_t)b * LATENT * NSEQ;

  for (int mi = 0; mi < 5; ++mi) {
    const int m0 = mi * 64;
    __syncthreads();  // protect Ws/T region from previous iter's readers
    // stage Wt tile [o][c] (float4), zero-pad o >= 288
    for (int e = tid; e < 64 * 48; e += 256) {
      int r = e / 48, cq = e % 48;
      int o = m0 + r;
      float4 wv = make_float4(0.f, 0.f, 0.f, 0.f);
      if (o < O3) wv = *(const float4*)(Wt + (size_t)o * NCH + 4 * cq);
      Ws[r * 200 + 4 * cq + 0] = f2bf(wv.x);
      Ws[r * 200 + 4 * cq + 1] = f2bf(wv.y);
      Ws[r * 200 + 4 * cq + 2] = f2bf(wv.z);
      Ws[r * 200 + 4 * cq + 3] = f2bf(wv.w);
    }
    __syncthreads();

    f32x4 acc[4];
    #pragma unroll
    for (int s = 0; s < 4; ++s) { acc[s][0]=0.f; acc[s][1]=0.f; acc[s][2]=0.f; acc[s][3]=0.f; }
    __builtin_amdgcn_s_setprio(1);
    #pragma unroll
    for (int kk = 0; kk < 6; ++kk) {
      short8 ax = *(const short8*)(Xs + (16 * wid + li) * 200 + 32 * kk + 8 * lg);
      #pragma unroll
      for (int sub = 0; sub < 4; ++sub) {
        short8 bw = *(const short8*)(Ws + (16 * sub + li) * 200 + 32 * kk + 8 * lg);
        acc[sub] = mfma16(ax, bw, acc[sub]);
      }
    }
    __builtin_amdgcn_s_setprio(0);
    __syncthreads();  // Ws reads done; safe to overwrite with T tiles

    // D row = n-within-wave (4lg+r), col = o-within-sub (li)
    #pragma unroll
    for (int sub = 0; sub < 4; ++sub) {
      int orel = 16 * sub + li;
      int o = m0 + orel;
      float bo = (o < O3) ? bt[o] : 0.f;
      #pragma unroll
      for (int r = 0; r < 4; ++r) {
        int nn = 16 * wid + 4 * lg + r;
        bf16_t bv = f2bf(acc[sub][r] + bo);
        Tts[nn * 72 + orel] = bv;
        if (o >= LATENT && o < 2 * LATENT) Tvs[orel * 72 + nn] = bv;
      }
    }
    __syncthreads();

    // coalesced global writes: tT rows (128B or 64B runs)
    const int W = (m0 + 64 <= O3) ? 64 : (O3 - m0);  // 64, last tile 32
    const int CPR = W / 8;
    for (int ch = tid; ch < 64 * CPR; ch += 256) {
      int row = ch / CPR, cc = ch % CPR;
      *(short8*)(tTb + (size_t)(n0 + row) * O3 + m0 + cc * 8) =
          *(const short8*)(Tts + row * 72 + cc * 8);
    }
    if (mi == 1 || mi == 2) {
      const int orelbase = (mi == 1) ? 32 : 0;
      const int vbase    = (mi == 1) ? 0  : 32;
      const int R        = (mi == 1) ? 32 : 64;
      for (int ch = tid; ch < R * 8; ch += 256) {
        int r = ch / 8, cc = ch % 8;
        *(short8*)(tVb + (size_t)(vbase + r) * NSEQ + n0 + cc * 8) =
            *(const short8*)(Tvs + (orelbase + r) * 72 + cc * 8);
      }
    }
  }
}

// ---------------------------------------------------------------------------
// K2: flash attention over q axis. 8 waves = 2 q-groups x 4 waves; 64 i/block.
// Group g handles q-tiles (2t+g)*64; private Qs/Vs per group, shared Ks.
// V stored PRE-PERMUTED so the PV A-fragment is one aligned ds_read_b128.
// Online softmax in-register (swapped QK^T), EXACT per-tile rescale (round-1
// semantics), scalar f2bf for P. Final cross-group merge in LDS; output
// aoT[b][n][96] (rows coalesced).
// ---------------------------------------------------------------------------
__global__ __launch_bounds__(512, 4) void k2_attn(const bf16_t* __restrict__ tT,
                                                  const bf16_t* __restrict__ tV,
                                                  bf16_t* __restrict__ aoT) {
  __shared__ __align__(16) char smem[67584];
  bf16_t* Ks  = (bf16_t*)smem;            // [64][104]  13312B
  bf16_t* Qs0 = (bf16_t*)(smem + 13312);  // [64][104]
  bf16_t* Qs1 = (bf16_t*)(smem + 26624);  // [64][104]
  bf16_t* Vs0 = (bf16_t*)(smem + 39936);  // [96][72]   13824B
  bf16_t* Vs1 = (bf16_t*)(smem + 53760);  // [96][72]

  const int tid = threadIdx.x;
  const int lane = tid & 63, li = lane & 15, lg = lane >> 4;
  const int wid = tid >> 6, g = wid >> 2, w4 = wid & 3;
  const int gtid = tid & 255;
  const int b = blockIdx.y, i0 = blockIdx.x * 64;

  const bf16_t* tTb = tT + (size_t)b * NSEQ * O3;
  const bf16_t* tVb = tV + (size_t)b * LATENT * NSEQ;

  // stage K tile once: Ks[i][c] = t[b][192+c][i0+i]
  for (int ch = tid; ch < 768; ch += 512) {
    int row = ch / 12, cc = ch % 12;
    *(short8*)(Ks + row * 104 + cc * 8) =
        *(const short8*)(tTb + (size_t)(i0 + row) * O3 + 2 * LATENT + cc * 8);
  }

  bf16_t* Qg = g ? Qs1 : Qs0;
  bf16_t* Vg = g ? Vs1 : Vs0;

  f32x4 Oa[6];
  #pragma unroll
  for (int s = 0; s < 6; ++s) { Oa[s][0]=0.f; Oa[s][1]=0.f; Oa[s][2]=0.f; Oa[s][3]=0.f; }
  float m_run = -3.0e38f, l_run = 0.f;
  const float c1 = 0.10206207261596575f;  // 1/sqrt(96)

  for (int t = 0; t < 32; ++t) {
    const int q0 = (2 * t + g) * 64;
    __syncthreads();  // prev-iter readers done before overwrite
    // stage Q tile (group-private): Qg[q][c]
    for (int ch = gtid; ch < 768; ch += 256) {
      int row = ch / 12, cc = ch % 12;
      *(short8*)(Qg + row * 104 + cc * 8) =
          *(const short8*)(tTb + (size_t)(q0 + row) * O3 + cc * 8);
    }
    // stage V tile pre-permuted: actual q = 32ks+16h+4lg2+j -> col = 32ks+8lg2+4h+j
    for (int ch = gtid; ch < 1536; ch += 256) {
      int c = ch >> 4, q4 = (ch & 15) * 4;
      int lg2 = (q4 >> 2) & 3, h = (q4 >> 4) & 1, ks = q4 >> 5;
      *(short4_t*)(Vg + c * 72 + ks * 32 + lg2 * 8 + h * 4) =
          *(const short4_t*)(tVb + (size_t)c * NSEQ + q0 + q4);
    }
    __syncthreads();

    // S'[q][i]: 64 q x this wave's 16 i  (A = Q rows, B = K rows)
    f32x4 S[4];
    #pragma unroll
    for (int s = 0; s < 4; ++s) { S[s][0]=0.f; S[s][1]=0.f; S[s][2]=0.f; S[s][3]=0.f; }
    __builtin_amdgcn_s_setprio(1);
    #pragma unroll
    for (int kk = 0; kk < 3; ++kk) {
      short8 bk = *(const short8*)(Ks + (16 * w4 + li) * 104 + 32 * kk + 8 * lg);
      #pragma unroll
      for (int s = 0; s < 4; ++s) {
        short8 aq = *(const short8*)(Qg + (16 * s + li) * 104 + 32 * kk + 8 * lg);
        S[s] = mfma16(aq, bk, S[s]);
      }
    }
    __builtin_amdgcn_s_setprio(0);

    // online softmax; lane holds q = 16s+4lg+r for one i  (EXACT rescale)
    float p[16];
    float tmax = -3.0e38f;
    #pragma unroll
    for (int s = 0; s < 4; ++s)
      #pragma unroll
      for (int r = 0; r < 4; ++r) {
        float v = S[s][r] * c1;
        p[4 * s + r] = v;
        tmax = fmaxf(tmax, v);
      }
    tmax = fmaxf(tmax, __shfl_xor(tmax, 16));
    tmax = fmaxf(tmax, __shfl_xor(tmax, 32));
    float mnew = fmaxf(m_run, tmax);
    float scl = __expf(m_run - mnew);
    float lsum = 0.f;
    #pragma unroll
    for (int k = 0; k < 16; ++k) {
      p[k] = __expf(p[k] - mnew);
      lsum += p[k];
    }
    lsum += __shfl_xor(lsum, 16);
    lsum += __shfl_xor(lsum, 32);
    l_run = l_run * scl + lsum;
    m_run = mnew;
    #pragma unroll
    for (int s = 0; s < 6; ++s) {
      Oa[s][0] *= scl; Oa[s][1] *= scl; Oa[s][2] *= scl; Oa[s][3] *= scl;
    }

    // PV: A-frag (lane,j) <-> V col q = 32ks+16(j>=4)+4lg+(j&3); B = p[8ks+j]
    __builtin_amdgcn_s_setprio(1);
    #pragma unroll
    for (int ks = 0; ks < 2; ++ks) {
      short8 bp;
      #pragma unroll
      for (int j = 0; j < 8; ++j) bp[j] = f2bf(p[8 * ks + j]);
      #pragma unroll
      for (int sub = 0; sub < 6; ++sub) {
        short8 av = *(const short8*)(Vg + (16 * sub + li) * 72 + ks * 32 + lg * 8);
        Oa[sub] = mfma16(av, bp, Oa[sub]);
      }
    }
    __builtin_amdgcn_s_setprio(0);
  }

  // ---- merge the two q-groups ----
  float* Op = (float*)(smem + 39936);           // [4][64][24] f32 (over Vs area)
  float* Ms = (float*)(smem + 39936 + 24576);   // [64]
  float* Ls = Ms + 64;
  __syncthreads();
  if (g == 1) {
    float* dst = Op + (w4 * 64 + lane) * 24;
    #pragma unroll
    for (int sub = 0; sub < 6; ++sub) *(f32x4*)(dst + 4 * sub) = Oa[sub];
    if (lg == 0) { Ms[w4 * 16 + li] = m_run; Ls[w4 * 16 + li] = l_run; }
  }
  __syncthreads();
  bf16_t* AoS = (bf16_t*)smem;  // [64][104] bounce (over Ks area)
  if (g == 0) {
    float m1 = Ms[w4 * 16 + li], l1 = Ls[w4 * 16 + li];
    const float* src = Op + (w4 * 64 + lane) * 24;
    float mM = fmaxf(m_run, m1);
    float s0 = __expf(m_run - mM), s1 = __expf(m1 - mM);
    float linv = 1.f / (l_run * s0 + l1 * s1);
    #pragma unroll
    for (int sub = 0; sub < 6; ++sub)
      #pragma unroll
      for (int r = 0; r < 4; ++r) {
        int c = 16 * sub + 4 * lg + r;
        float val = (Oa[sub][r] * s0 + src[4 * sub + r] * s1) * linv;
        AoS[(16 * w4 + li) * 104 + c] = f2bf(val);
      }
  }
  __syncthreads();
  bf16_t* aoTb = aoT + (size_t)b * NSEQ * LATENT;
  for (int ch = tid; ch < 768; ch += 512) {
    int row = ch / 12, cc = ch % 12;
    *(short8*)(aoTb + (size_t)(i0 + row) * LATENT + cc * 8) =
        *(const short8*)(AoS + row * 104 + cc * 8);
  }
}

// ---------------------------------------------------------------------------
// K3: out = Wd @ ao + bd + x  (192x96 @ 96x4096 per batch, f32 out)
// aoT rows are [n][96] -> staging is straight coalesced short8.
// LDS-bounce f32 epilogue -> float4 x-read and out-write.
// Explicit single LDS block so the Os alias is guaranteed in-bounds.
// ---------------------------------------------------------------------------
__global__ __launch_bounds__(256) void k3_proj(const bf16_t* __restrict__ aoT,
                                               const float* __restrict__ Wd,
                                               const float* __restrict__ bd,
                                               const float* __restrict__ x,
                                               float* __restrict__ out) {
  const int tid = threadIdx.x;
  const int li = tid & 15, lg = (tid >> 4) & 3, wid = tid >> 6;
  const int b = blockIdx.z, m0 = blockIdx.y * 64, n0 = blockIdx.x * 64;

  __shared__ __align__(16) char sm3[26624];
  bf16_t* Ws = (bf16_t*)sm3;            // [64][104] Wd tile [o][c]
  bf16_t* As = (bf16_t*)(sm3 + 13312);  // [64][104] aoT tile [n][c]
  float*  Os = (float*)sm3;             // [64][68] f32 bounce (17408B <= 26624B)

  const bf16_t* aob = aoT + (size_t)b * NSEQ * LATENT;
  for (int ch = tid; ch < 768; ch += 256) {
    int row = ch / 12, cc = ch % 12;
    *(short8*)(As + row * 104 + cc * 8) =
        *(const short8*)(aob + (size_t)(n0 + row) * LATENT + cc * 8);
  }
  for (int e = tid; e < 64 * 24; e += 256) {
    int r = e / 24, cq = e % 24;
    float4 wv = *(const float4*)(Wd + (size_t)(m0 + r) * LATENT + 4 * cq);
    Ws[r * 104 + 4 * cq + 0] = f2bf(wv.x);
    Ws[r * 104 + 4 * cq + 1] = f2bf(wv.y);
    Ws[r * 104 + 4 * cq + 2] = f2bf(wv.z);
    Ws[r * 104 + 4 * cq + 3] = f2bf(wv.w);
  }
  __syncthreads();

  f32x4 acc[4];
  #pragma unroll
  for (int s = 0; s < 4; ++s) { acc[s][0]=0.f; acc[s][1]=0.f; acc[s][2]=0.f; acc[s][3]=0.f; }
  __builtin_amdgcn_s_setprio(1);
  #pragma unroll
  for (int kk = 0; kk < 3; ++kk) {
    short8 aw = *(const short8*)(Ws + (16 * wid + li) * 104 + 32 * kk + 8 * lg);
    #pragma unroll
    for (int sub = 0; sub < 4; ++sub) {
      short8 ba = *(const short8*)(As + (16 * sub + li) * 104 + 32 * kk + 8 * lg);
      acc[sub] = mfma16(aw, ba, acc[sub]);
    }
  }
  __builtin_amdgcn_s_setprio(0);
  __syncthreads();  // Ws/As reads done; safe to overwrite with Os

  // D row = o-within-wave (4lg+r), col = n-within-sub (li)
  #pragma unroll
  for (int sub = 0; sub < 4; ++sub)
    #pragma unroll
    for (int r = 0; r < 4; ++r) {
      int o = 16 * wid + 4 * lg + r;
      Os[o * 68 + 16 * sub + li] = acc[sub][r] + bd[m0 + o];
    }
  __syncthreads();

  const float* xb = x + ((size_t)b * NCH + m0) * NSEQ + n0;
  float* ob = out + ((size_t)b * NCH + m0) * NSEQ + n0;
  for (int ch = tid; ch < 64 * 16; ch += 256) {
    int row = ch >> 4, cq = ch & 15;
    float4 xv = *(const float4*)(xb + (size_t)row * NSEQ + 4 * cq);
    const float* os = Os + row * 68 + 4 * cq;
    float4 r4;
    r4.x = os[0] + xv.x;
    r4.y = os[1] + xv.y;
    r4.z = os[2] + xv.z;
    r4.w = os[3] + xv.w;
    *(float4*)(ob + (size_t)row * NSEQ + 4 * cq) = r4;
  }
}

// ---------------------------------------------------------------------------
extern "C" void kernel_launch(void* const* d_in, const int* in_sizes, int n_in,
                              void* d_out, int out_size, void* d_ws, size_t ws_size,
                              hipStream_t stream) {
  const float* x  = (const float*)d_in[0];
  const float* Wt = (const float*)d_in[1];
  const float* bt = (const float*)d_in[2];
  const float* Wd = (const float*)d_in[3];
  const float* bd = (const float*)d_in[4];
  float* out = (float*)d_out;

  char* ws = (char*)d_ws;
  const size_t tT_bytes = (size_t)NB * NSEQ * O3 * 2;       // 18,874,368
  const size_t tV_bytes = (size_t)NB * LATENT * NSEQ * 2;   //  6,291,456
  bf16_t* tT  = (bf16_t*)ws;
  bf16_t* tV  = (bf16_t*)(ws + tT_bytes);
  bf16_t* aoT = (bf16_t*)(ws + tT_bytes + tV_bytes);        // [b][n][96]

  k1_qkv<<<dim3(64, NB), dim3(256), 0, stream>>>(x, Wt, bt, tT, tV);
  k2_attn<<<dim3(64, NB), dim3(512), 0, stream>>>(tT, tV, aoT);
  k3_proj<<<dim3(64, 3, NB), dim3(256), 0, stream>>>(aoT, Wd, bd, x, out);
}

// Round 4
// 193.681 us; speedup vs baseline: 1.7567x; 1.3818x over previous
//
#include <hip/hip_runtime.h>

#define LATENT 96
#define NCH    192
#define O3     288
#define NSEQ   4096
#define NB     8

typedef short bf16_t;  // bf16 storage as raw bits
typedef __attribute__((ext_vector_type(8))) short  short8;
typedef __attribute__((ext_vector_type(4))) short  short4_t;
typedef __attribute__((ext_vector_type(4))) float  f32x4;

#define C2SCALE 0.14724447f  // (1/sqrt(96)) * log2(e)

__device__ __forceinline__ short f2bf(float f) {
  union { float f; unsigned u; } v; v.f = f;
  unsigned r = v.u + 0x7FFFu + ((v.u >> 16) & 1u);  // RNE, finite inputs
  return (short)(r >> 16);
}

__device__ __forceinline__ unsigned pk2bf(float lo, float hi) {
  unsigned r;
  asm("v_cvt_pk_bf16_f32 %0, %1, %2" : "=v"(r) : "v"(lo), "v"(hi));
  return r;  // r.lo16 = bf16(lo), r.hi16 = bf16(hi), RNE
}

__device__ __forceinline__ f32x4 mfma16(short8 a, short8 b, f32x4 c) {
  return __builtin_amdgcn_mfma_f32_16x16x32_bf16(a, b, c, 0, 0, 0);
}

// ---------------------------------------------------------------------------
// K1: t = Wt @ x + bt  (per batch, 288x192 @ 192x4096)
// One block per (b, n-tile of 64); x staged ONCE; loop 5 m-tiles of 64.
// K channels (o in [192,288)) are PRE-SCALED by C2SCALE for k2's exp2 softmax.
// ---------------------------------------------------------------------------
__global__ __launch_bounds__(256) void k1_qkv(const float* __restrict__ x,
                                              const float* __restrict__ Wt,
                                              const float* __restrict__ bt,
                                              bf16_t* __restrict__ tT,
                                              bf16_t* __restrict__ tV) {
  const int tid = threadIdx.x;
  const int li = tid & 15, lg = (tid >> 4) & 3, wid = tid >> 6;
  const int b = blockIdx.y, n0 = blockIdx.x * 64;

  __shared__ __align__(16) char sm1[51200];
  bf16_t* Xs = (bf16_t*)sm1;              // [64][200] x^T tile [n][c]
  bf16_t* Ws = (bf16_t*)(sm1 + 25600);    // [64][200] Wt tile [o][c]
  bf16_t* Tts = Ws;                        // [64][72]  bounce [n][o]
  bf16_t* Tvs = Ws + 64 * 72;              // [64][72]  bounce [o][n]

  const float* xb = x + (size_t)b * NCH * NSEQ + n0;
  for (int e = tid; e < NCH * 16; e += 256) {
    int c = e >> 4, nq = e & 15;
    float4 xv = *(const float4*)(xb + (size_t)c * NSEQ + nq * 4);
    Xs[(4 * nq + 0) * 200 + c] = f2bf(xv.x);
    Xs[(4 * nq + 1) * 200 + c] = f2bf(xv.y);
    Xs[(4 * nq + 2) * 200 + c] = f2bf(xv.z);
    Xs[(4 * nq + 3) * 200 + c] = f2bf(xv.w);
  }

  bf16_t* tTb = tT + (size_t)b * NSEQ * O3;
  bf16_t* tVb = tV + (size_t)b * LATENT * NSEQ;

  for (int mi = 0; mi < 5; ++mi) {
    const int m0 = mi * 64;
    __syncthreads();
    for (int e = tid; e < 64 * 48; e += 256) {
      int r = e / 48, cq = e % 48;
      int o = m0 + r;
      float4 wv = make_float4(0.f, 0.f, 0.f, 0.f);
      if (o < O3) wv = *(const float4*)(Wt + (size_t)o * NCH + 4 * cq);
      Ws[r * 200 + 4 * cq + 0] = f2bf(wv.x);
      Ws[r * 200 + 4 * cq + 1] = f2bf(wv.y);
      Ws[r * 200 + 4 * cq + 2] = f2bf(wv.z);
      Ws[r * 200 + 4 * cq + 3] = f2bf(wv.w);
    }
    __syncthreads();

    f32x4 acc[4];
    #pragma unroll
    for (int s = 0; s < 4; ++s) { acc[s][0]=0.f; acc[s][1]=0.f; acc[s][2]=0.f; acc[s][3]=0.f; }
    __builtin_amdgcn_s_setprio(1);
    #pragma unroll
    for (int kk = 0; kk < 6; ++kk) {
      short8 ax = *(const short8*)(Xs + (16 * wid + li) * 200 + 32 * kk + 8 * lg);
      #pragma unroll
      for (int sub = 0; sub < 4; ++sub) {
        short8 bw = *(const short8*)(Ws + (16 * sub + li) * 200 + 32 * kk + 8 * lg);
        acc[sub] = mfma16(ax, bw, acc[sub]);
      }
    }
    __builtin_amdgcn_s_setprio(0);
    __syncthreads();

    #pragma unroll
    for (int sub = 0; sub < 4; ++sub) {
      int orel = 16 * sub + li;
      int o = m0 + orel;
      float bo = (o < O3) ? bt[o] : 0.f;
      #pragma unroll
      for (int r = 0; r < 4; ++r) {
        int nn = 16 * wid + 4 * lg + r;
        float v = acc[sub][r] + bo;
        bf16_t bv = f2bf(o >= 2 * LATENT ? v * C2SCALE : v);
        Tts[nn * 72 + orel] = bv;
        if (o >= LATENT && o < 2 * LATENT) Tvs[orel * 72 + nn] = bv;
      }
    }
    __syncthreads();

    const int W = (m0 + 64 <= O3) ? 64 : (O3 - m0);
    const int CPR = W / 8;
    for (int ch = tid; ch < 64 * CPR; ch += 256) {
      int row = ch / CPR, cc = ch % CPR;
      *(short8*)(tTb + (size_t)(n0 + row) * O3 + m0 + cc * 8) =
          *(const short8*)(Tts + row * 72 + cc * 8);
    }
    if (mi == 1 || mi == 2) {
      const int orelbase = (mi == 1) ? 32 : 0;
      const int vbase    = (mi == 1) ? 0  : 32;
      const int R        = (mi == 1) ? 32 : 64;
      for (int ch = tid; ch < R * 8; ch += 256) {
        int r = ch / 8, cc = ch % 8;
        *(short8*)(tVb + (size_t)(vbase + r) * NSEQ + n0 + cc * 8) =
            *(const short8*)(Tvs + (orelbase + r) * 72 + cc * 8);
      }
    }
  }
}

// ---------------------------------------------------------------------------
// K2: flash attention over q axis. 8 waves = 2 q-groups x 4 waves.
// Block covers 128 i (Iq=32 per wave, two 16-i halves sharing Q/V fragments).
// K fragments in REGISTERS (loaded once from global). Q/V staged in LDS with
// register prefetch (issue-early / write-late). S comes out pre-scaled in
// log2 domain (K pre-scaled in k1) -> softmax uses exp2 directly.
// ---------------------------------------------------------------------------
__global__ __launch_bounds__(512, 1) void k2_attn(const bf16_t* __restrict__ tT,
                                                  const bf16_t* __restrict__ tV,
                                                  bf16_t* __restrict__ aoT) {
  __shared__ __align__(16) char smem[54272];
  bf16_t* Qs0 = (bf16_t*)smem;             // [64][104] 13312B
  bf16_t* Qs1 = (bf16_t*)(smem + 13312);
  bf16_t* Vs0 = (bf16_t*)(smem + 26624);   // [96][72]  13824B
  bf16_t* Vs1 = (bf16_t*)(smem + 40448);   // end 54272

  const int tid = threadIdx.x;
  const int lane = tid & 63, li = lane & 15, lg = lane >> 4;
  const int wid = tid >> 6, g = wid >> 2, w4 = wid & 3;
  const int gt = tid & 255;

  // XCD-aware remap: each XCD's 32 blocks share one batch's tT/tV (L2-fit)
  const int myid = blockIdx.x + 32 * blockIdx.y;
  const int b = myid & 7;
  const int i0 = (myid >> 3) * 128;

  const bf16_t* tTb = tT + (size_t)b * NSEQ * O3;
  const bf16_t* tVb = tV + (size_t)b * LATENT * NSEQ;

  // K fragments in registers for the whole kernel (i = i0+32*w4+16*ib+li)
  short8 kb[2][3];
  #pragma unroll
  for (int ib = 0; ib < 2; ++ib)
    #pragma unroll
    for (int kk = 0; kk < 3; ++kk)
      kb[ib][kk] = *(const short8*)(tTb +
          (size_t)(i0 + 32 * w4 + 16 * ib + li) * O3 + 2 * LATENT + 32 * kk + 8 * lg);

  bf16_t* Qg = g ? Qs1 : Qs0;
  bf16_t* Vg = g ? Vs1 : Vs0;

  // staging offsets (per-thread, loop-invariant)
  int qlds[3], qglb[3], vlds[6], vglb[6];
  #pragma unroll
  for (int h = 0; h < 3; ++h) {
    int id = gt + 256 * h, row = id / 12, cc = id % 12;
    qlds[h] = row * 104 + cc * 8;
    qglb[h] = row * O3 + cc * 8;
  }
  #pragma unroll
  for (int h = 0; h < 6; ++h) {
    int id = gt + 256 * h, c = id >> 4, q4 = (id & 15) * 4;
    int lg2 = (q4 >> 2) & 3, hh = (q4 >> 4) & 1, ks = q4 >> 5;
    vlds[h] = c * 72 + ks * 32 + lg2 * 8 + hh * 4;
    vglb[h] = c * NSEQ + q4;
  }

  short8 qr[3];
  short4_t vr[6];
  {  // prologue: loads for tile t=0
    const int q0 = g * 64;
    #pragma unroll
    for (int h = 0; h < 3; ++h)
      qr[h] = *(const short8*)(tTb + (size_t)q0 * O3 + qglb[h]);
    #pragma unroll
    for (int h = 0; h < 6; ++h)
      vr[h] = *(const short4_t*)(tVb + q0 + vglb[h]);
  }

  f32x4 Oa[2][6];
  #pragma unroll
  for (int ib = 0; ib < 2; ++ib)
    #pragma unroll
    for (int s = 0; s < 6; ++s) { Oa[ib][s][0]=0.f; Oa[ib][s][1]=0.f; Oa[ib][s][2]=0.f; Oa[ib][s][3]=0.f; }
  float m2[2] = {-3.0e38f, -3.0e38f};
  float l[2] = {0.f, 0.f};

  for (int t = 0; t < 32; ++t) {
    __syncthreads();  // prev-iter LDS readers done
    #pragma unroll
    for (int h = 0; h < 3; ++h) *(short8*)(Qg + qlds[h]) = qr[h];
    #pragma unroll
    for (int h = 0; h < 6; ++h) *(short4_t*)(Vg + vlds[h]) = vr[h];
    __syncthreads();  // tile visible to all group waves

    if (t < 31) {  // prefetch next tile (lands during compute)
      const int q0n = (2 * (t + 1) + g) * 64;
      #pragma unroll
      for (int h = 0; h < 3; ++h)
        qr[h] = *(const short8*)(tTb + (size_t)q0n * O3 + qglb[h]);
      #pragma unroll
      for (int h = 0; h < 6; ++h)
        vr[h] = *(const short4_t*)(tVb + q0n + vglb[h]);
    }

    // S'[q][i] for 64 q x 32 i (two 16-i halves share aq fragments)
    f32x4 S[2][4];
    #pragma unroll
    for (int ib = 0; ib < 2; ++ib)
      #pragma unroll
      for (int s = 0; s < 4; ++s) { S[ib][s][0]=0.f; S[ib][s][1]=0.f; S[ib][s][2]=0.f; S[ib][s][3]=0.f; }
    __builtin_amdgcn_s_setprio(1);
    #pragma unroll
    for (int kk = 0; kk < 3; ++kk) {
      short8 aq[4];
      #pragma unroll
      for (int s = 0; s < 4; ++s)
        aq[s] = *(const short8*)(Qg + (16 * s + li) * 104 + 32 * kk + 8 * lg);
      #pragma unroll
      for (int ib = 0; ib < 2; ++ib)
        #pragma unroll
        for (int s = 0; s < 4; ++s)
          S[ib][s] = mfma16(aq[s], kb[ib][kk], S[ib][s]);
    }
    __builtin_amdgcn_s_setprio(0);

    // online softmax per i-half (values already in log2 domain)
    float p[2][16];
    #pragma unroll
    for (int ib = 0; ib < 2; ++ib) {
      float tm = S[ib][0][0];
      #pragma unroll
      for (int s = 0; s < 4; ++s)
        #pragma unroll
        for (int r = 0; r < 4; ++r) {
          p[ib][4 * s + r] = S[ib][s][r];
          tm = fmaxf(tm, S[ib][s][r]);
        }
      tm = fmaxf(tm, __shfl_xor(tm, 16));
      tm = fmaxf(tm, __shfl_xor(tm, 32));
      float mnew = fmaxf(m2[ib], tm);
      float scl = __builtin_amdgcn_exp2f(m2[ib] - mnew);
      float ls = 0.f;
      #pragma unroll
      for (int k = 0; k < 16; ++k) {
        p[ib][k] = __builtin_amdgcn_exp2f(p[ib][k] - mnew);
        ls += p[ib][k];
      }
      ls += __shfl_xor(ls, 16);
      ls += __shfl_xor(ls, 32);
      l[ib] = l[ib] * scl + ls;
      m2[ib] = mnew;
      #pragma unroll
      for (int s = 0; s < 6; ++s) {
        Oa[ib][s][0] *= scl; Oa[ib][s][1] *= scl; Oa[ib][s][2] *= scl; Oa[ib][s][3] *= scl;
      }
    }

    // PV: shared V fragments feed both i-halves
    __builtin_amdgcn_s_setprio(1);
    #pragma unroll
    for (int ks = 0; ks < 2; ++ks) {
      union { unsigned u[4]; short8 s8; } bp0, bp1;
      #pragma unroll
      for (int j = 0; j < 4; ++j) {
        bp0.u[j] = pk2bf(p[0][8 * ks + 2 * j], p[0][8 * ks + 2 * j + 1]);
        bp1.u[j] = pk2bf(p[1][8 * ks + 2 * j], p[1][8 * ks + 2 * j + 1]);
      }
      #pragma unroll
      for (int sub = 0; sub < 6; ++sub) {
        short8 av = *(const short8*)(Vg + (16 * sub + li) * 72 + ks * 32 + lg * 8);
        Oa[0][sub] = mfma16(av, bp0.s8, Oa[0][sub]);
        Oa[1][sub] = mfma16(av, bp1.s8, Oa[1][sub]);
      }
    }
    __builtin_amdgcn_s_setprio(0);
  }

  // ---- merge the two q-groups ----
  float* Op = (float*)smem;              // [4][64][2][24] f32 = 49152B
  float* Ms = (float*)(smem + 49152);    // [128]
  float* Ls = Ms + 128;                  // [128]
  __syncthreads();
  if (g == 1) {
    #pragma unroll
    for (int ib = 0; ib < 2; ++ib) {
      float* dst = Op + (size_t)((w4 * 64 + lane) * 2 + ib) * 24;
      #pragma unroll
      for (int sub = 0; sub < 6; ++sub) *(f32x4*)(dst + 4 * sub) = Oa[ib][sub];
      if (lg == 0) {
        int ir = 32 * w4 + 16 * ib + li;
        Ms[ir] = m2[ib]; Ls[ir] = l[ib];
      }
    }
  }
  __syncthreads();
  if (g == 0) {  // merge into Oa regs (reads only)
    #pragma unroll
    for (int ib = 0; ib < 2; ++ib) {
      int ir = 32 * w4 + 16 * ib + li;
      float m1 = Ms[ir], l1 = Ls[ir];
      const float* src = Op + (size_t)((w4 * 64 + lane) * 2 + ib) * 24;
      float mM = fmaxf(m2[ib], m1);
      float s0 = __builtin_amdgcn_exp2f(m2[ib] - mM);
      float s1 = __builtin_amdgcn_exp2f(m1 - mM);
      float linv = 1.f / (l[ib] * s0 + l1 * s1);
      #pragma unroll
      for (int sub = 0; sub < 6; ++sub)
        #pragma unroll
        for (int r = 0; r < 4; ++r)
          Oa[ib][sub][r] = (Oa[ib][sub][r] * s0 + src[4 * sub + r] * s1) * linv;
    }
  }
  __syncthreads();  // all Op reads done; region reusable
  bf16_t* AoS = (bf16_t*)smem;  // [128][104]
  if (g == 0) {
    #pragma unroll
    for (int ib = 0; ib < 2; ++ib) {
      int ir = 32 * w4 + 16 * ib + li;
      #pragma unroll
      for (int sub = 0; sub < 6; ++sub)
        #pragma unroll
        for (int r = 0; r < 4; ++r)
          AoS[ir * 104 + 16 * sub + 4 * lg + r] = f2bf(Oa[ib][sub][r]);
    }
  }
  __syncthreads();
  bf16_t* aoTb = aoT + (size_t)b * NSEQ * LATENT;
  for (int ch = tid; ch < 1536; ch += 512) {
    int row = ch / 12, cc = ch % 12;
    *(short8*)(aoTb + (size_t)(i0 + row) * LATENT + cc * 8) =
        *(const short8*)(AoS + row * 104 + cc * 8);
  }
}

// ---------------------------------------------------------------------------
// K3: out = Wd @ ao + bd + x  (192x96 @ 96x4096 per batch, f32 out)
// ---------------------------------------------------------------------------
__global__ __launch_bounds__(256) void k3_proj(const bf16_t* __restrict__ aoT,
                                               const float* __restrict__ Wd,
                                               const float* __restrict__ bd,
                                               const float* __restrict__ x,
                                               float* __restrict__ out) {
  const int tid = threadIdx.x;
  const int li = tid & 15, lg = (tid >> 4) & 3, wid = tid >> 6;
  const int b = blockIdx.z, m0 = blockIdx.y * 64, n0 = blockIdx.x * 64;

  __shared__ __align__(16) char sm3[26624];
  bf16_t* Ws = (bf16_t*)sm3;            // [64][104]
  bf16_t* As = (bf16_t*)(sm3 + 13312);  // [64][104]
  float*  Os = (float*)sm3;             // [64][68] f32 bounce

  const bf16_t* aob = aoT + (size_t)b * NSEQ * LATENT;
  for (int ch = tid; ch < 768; ch += 256) {
    int row = ch / 12, cc = ch % 12;
    *(short8*)(As + row * 104 + cc * 8) =
        *(const short8*)(aob + (size_t)(n0 + row) * LATENT + cc * 8);
  }
  for (int e = tid; e < 64 * 24; e += 256) {
    int r = e / 24, cq = e % 24;
    float4 wv = *(const float4*)(Wd + (size_t)(m0 + r) * LATENT + 4 * cq);
    Ws[r * 104 + 4 * cq + 0] = f2bf(wv.x);
    Ws[r * 104 + 4 * cq + 1] = f2bf(wv.y);
    Ws[r * 104 + 4 * cq + 2] = f2bf(wv.z);
    Ws[r * 104 + 4 * cq + 3] = f2bf(wv.w);
  }
  __syncthreads();

  f32x4 acc[4];
  #pragma unroll
  for (int s = 0; s < 4; ++s) { acc[s][0]=0.f; acc[s][1]=0.f; acc[s][2]=0.f; acc[s][3]=0.f; }
  __builtin_amdgcn_s_setprio(1);
  #pragma unroll
  for (int kk = 0; kk < 3; ++kk) {
    short8 aw = *(const short8*)(Ws + (16 * wid + li) * 104 + 32 * kk + 8 * lg);
    #pragma unroll
    for (int sub = 0; sub < 4; ++sub) {
      short8 ba = *(const short8*)(As + (16 * sub + li) * 104 + 32 * kk + 8 * lg);
      acc[sub] = mfma16(aw, ba, acc[sub]);
    }
  }
  __builtin_amdgcn_s_setprio(0);
  __syncthreads();

  #pragma unroll
  for (int sub = 0; sub < 4; ++sub)
    #pragma unroll
    for (int r = 0; r < 4; ++r) {
      int o = 16 * wid + 4 * lg + r;
      Os[o * 68 + 16 * sub + li] = acc[sub][r] + bd[m0 + o];
    }
  __syncthreads();

  const float* xb = x + ((size_t)b * NCH + m0) * NSEQ + n0;
  float* ob = out + ((size_t)b * NCH + m0) * NSEQ + n0;
  for (int ch = tid; ch < 64 * 16; ch += 256) {
    int row = ch >> 4, cq = ch & 15;
    float4 xv = *(const float4*)(xb + (size_t)row * NSEQ + 4 * cq);
    const float* os = Os + row * 68 + 4 * cq;
    float4 r4;
    r4.x = os[0] + xv.x;
    r4.y = os[1] + xv.y;
    r4.z = os[2] + xv.z;
    r4.w = os[3] + xv.w;
    *(float4*)(ob + (size_t)row * NSEQ + 4 * cq) = r4;
  }
}

// ---------------------------------------------------------------------------
extern "C" void kernel_launch(void* const* d_in, const int* in_sizes, int n_in,
                              void* d_out, int out_size, void* d_ws, size_t ws_size,
                              hipStream_t stream) {
  const float* x  = (const float*)d_in[0];
  const float* Wt = (const float*)d_in[1];
  const float* bt = (const float*)d_in[2];
  const float* Wd = (const float*)d_in[3];
  const float* bd = (const float*)d_in[4];
  float* out = (float*)d_out;

  char* ws = (char*)d_ws;
  const size_t tT_bytes = (size_t)NB * NSEQ * O3 * 2;       // 18,874,368
  const size_t tV_bytes = (size_t)NB * LATENT * NSEQ * 2;   //  6,291,456
  bf16_t* tT  = (bf16_t*)ws;
  bf16_t* tV  = (bf16_t*)(ws + tT_bytes);
  bf16_t* aoT = (bf16_t*)(ws + tT_bytes + tV_bytes);        // [b][n][96]

  k1_qkv<<<dim3(64, NB), dim3(256), 0, stream>>>(x, Wt, bt, tT, tV);
  k2_attn<<<dim3(32, NB), dim3(512), 0, stream>>>(tT, tV, aoT);
  k3_proj<<<dim3(64, 3, NB), dim3(256), 0, stream>>>(aoT, Wd, bd, x, out);
}